// Round 17
// baseline (181.418 us; speedup 1.0000x reference)
//
#include <hip/hip_runtime.h>
#include <math.h>

#ifndef M_PI
#define M_PI 3.14159265358979323846
#endif

typedef float fx4 __attribute__((ext_vector_type(4)));
typedef __bf16 bf16x8 __attribute__((ext_vector_type(8)));
typedef __bf16 bf16x4 __attribute__((ext_vector_type(4)));

__device__ __forceinline__ unsigned short f2bf(float f){
  union { float f; unsigned u; } v; v.f = f;
  unsigned r = v.u + 0x7FFFu + ((v.u >> 16) & 1u);
  return (unsigned short)(r >> 16);
}
__device__ __forceinline__ float bf2f(unsigned short u){
  union { unsigned u; float f; } v; v.u = ((unsigned)u) << 16;
  return v.f;
}
// swizzled byte offset within a [row][128] bf16 tile (256 B rows)
__device__ __forceinline__ int swz(int row, int colbyte){
  return row*256 + (colbyte ^ ((row & 7) << 4));
}
// load 8 fp32 -> bf16x8 fragment (RNE, same as f2bf)
__device__ __forceinline__ bf16x8 f8tobf(const float* p){
  float4 a = *(const float4*)p;
  float4 b = *(const float4*)(p+4);
  bf16x8 r;
  r[0]=(__bf16)a.x; r[1]=(__bf16)a.y; r[2]=(__bf16)a.z; r[3]=(__bf16)a.w;
  r[4]=(__bf16)b.x; r[5]=(__bf16)b.y; r[6]=(__bf16)b.z; r[7]=(__bf16)b.w;
  return r;
}

// Double-buffered 128-deep (per-wave 64x64) MFMA GEMM core.
template<typename FA, typename FB>
__device__ __forceinline__ void run_gemm(FA la, FB lb, fx4 (&acc)[4][4]){
  bf16x8 a[2][4], b[2][4];
  #pragma unroll
  for (int mi=0;mi<4;mi++){ a[0][mi]=la(mi,0); b[0][mi]=lb(mi,0); }
  #pragma unroll
  for (int ks=0; ks<4; ks++){
    int cur = ks&1, nxt = cur^1;
    if (ks<3){
      #pragma unroll
      for (int mi=0;mi<4;mi++){ a[nxt][mi]=la(mi,ks+1); b[nxt][mi]=lb(mi,ks+1); }
    }
    #pragma unroll
    for (int mi=0;mi<4;mi++)
      #pragma unroll
      for (int ni=0;ni<4;ni++)
        acc[mi][ni] = __builtin_amdgcn_mfma_f32_16x16x32_bf16(a[cur][mi], b[cur][ni], acc[mi][ni], 0, 0, 0);
  }
}

// Two-tile pair, shared B operand: acc0 = A0*B, acc1 = A1*B.
template<typename FA0, typename FA1, typename FB>
__device__ __forceinline__ void run_pair_sharedB(FA0 la0, FA1 la1, FB lb,
                                                 fx4 (&acc0)[4][4], fx4 (&acc1)[4][4]){
  bf16x8 a0[2][4], a1[2][4], b[2][4];
  #pragma unroll
  for (int mi=0;mi<4;mi++){ a0[0][mi]=la0(mi,0); a1[0][mi]=la1(mi,0); b[0][mi]=lb(mi,0); }
  #pragma unroll
  for (int ks=0; ks<4; ks++){
    int cur = ks&1, nxt = cur^1;
    if (ks<3){
      #pragma unroll
      for (int mi=0;mi<4;mi++){ a0[nxt][mi]=la0(mi,ks+1); a1[nxt][mi]=la1(mi,ks+1); b[nxt][mi]=lb(mi,ks+1); }
    }
    #pragma unroll
    for (int mi=0;mi<4;mi++)
      #pragma unroll
      for (int ni=0;ni<4;ni++){
        acc0[mi][ni] = __builtin_amdgcn_mfma_f32_16x16x32_bf16(a0[cur][mi], b[cur][ni], acc0[mi][ni], 0, 0, 0);
        acc1[mi][ni] = __builtin_amdgcn_mfma_f32_16x16x32_bf16(a1[cur][mi], b[cur][ni], acc1[mi][ni], 0, 0, 0);
      }
  }
}

// Two-tile pair, shared A operand: acc0 = A*B0, acc1 = A*B1.
template<typename FA, typename FB0, typename FB1>
__device__ __forceinline__ void run_pair_sharedA(FA la, FB0 lb0, FB1 lb1,
                                                 fx4 (&acc0)[4][4], fx4 (&acc1)[4][4]){
  bf16x8 a[2][4], b0[2][4], b1[2][4];
  #pragma unroll
  for (int mi=0;mi<4;mi++){ a[0][mi]=la(mi,0); b0[0][mi]=lb0(mi,0); b1[0][mi]=lb1(mi,0); }
  #pragma unroll
  for (int ks=0; ks<4; ks++){
    int cur = ks&1, nxt = cur^1;
    if (ks<3){
      #pragma unroll
      for (int mi=0;mi<4;mi++){ a[nxt][mi]=la(mi,ks+1); b0[nxt][mi]=lb0(mi,ks+1); b1[nxt][mi]=lb1(mi,ks+1); }
    }
    #pragma unroll
    for (int mi=0;mi<4;mi++)
      #pragma unroll
      for (int ni=0;ni<4;ni++){
        acc0[mi][ni] = __builtin_amdgcn_mfma_f32_16x16x32_bf16(a[cur][mi], b0[cur][ni], acc0[mi][ni], 0, 0, 0);
        acc1[mi][ni] = __builtin_amdgcn_mfma_f32_16x16x32_bf16(a[cur][mi], b1[cur][ni], acc1[mi][ni], 0, 0, 0);
      }
  }
}

// == K1: prep (0..127) || dwconv (128..4223) || projk (4224..4351, fp32 inline-cast) ==
__global__ __launch_bounds__(256) void k1_prep_conv_projk(
    const float* __restrict__ in_w, const float* __restrict__ ph_w,
    const float* __restrict__ out_w, const float* __restrict__ fe,
    const float* __restrict__ x, const float* __restrict__ dw_w,
    const float* __restrict__ dw_b,
    unsigned short* __restrict__ basis_bf, unsigned short* __restrict__ basisT_bf,
    unsigned short* __restrict__ in_w_bf, unsigned short* __restrict__ out_w_bf,
    unsigned short* __restrict__ conv, float* __restrict__ projT)
{
  int blk = blockIdx.x;
  int t = threadIdx.x;
  if (blk < 128){
    // ---- prep ----
    if (t >= 128) return;
    int n = blk, h = t;
    double arg = (double)(n*(2*h+1)) * (M_PI/256.0);
    double v = cos(arg) * 0.125;
    if (n==0) v *= 0.7071067811865476;
    unsigned short bv = f2bf((float)v);
    basis_bf[n*128+h]  = bv;
    basisT_bf[h*128+n] = bv;
    in_w_bf[n*128+h]        = f2bf(in_w[n*128+h]);
    in_w_bf[(n+128)*128+h]  = f2bf(in_w[(n+128)*128+h]);
    out_w_bf[n*128+h]       = f2bf(out_w[n*128+h]);
    return;
  }
  if (blk >= 4224){
    // ---- projk: proj = fe[16384,128] @ ph_w^T -> projT[c][r], fp32 operands inline-cast
    int r0 = (blk - 4224) * 128;
    int l = t & 63, wid = t >> 6;
    int wm = wid >> 1, wn = wid & 1;
    int lr = l & 15, lk = (l>>4)*8, ld4 = (l>>4)*4;
    fx4 acc[4][4];
    #pragma unroll
    for (int i=0;i<4;i++) for (int j=0;j<4;j++) acc[i][j] = (fx4){0.f,0.f,0.f,0.f};
    run_gemm(
      [&](int mi,int ks)->bf16x8{ return f8tobf(fe + (size_t)(r0 + wm*64+mi*16+lr)*128 + ks*32+lk); },
      [&](int ni,int ks)->bf16x8{ return f8tobf(ph_w + (size_t)(wn*64+ni*16+lr)*128 + ks*32+lk); },
      acc);
    #pragma unroll
    for (int mi=0;mi<4;mi++)
      #pragma unroll
      for (int ni=0;ni<4;ni++){
        int c = wn*64 + ni*16 + lr;
        int r = r0 + wm*64 + mi*16 + ld4;
        *(fx4*)(projT + (size_t)c*16384 + r) = acc[mi][ni];
      }
    return;
  }
  // ---- dwconv ----
  {
    int bb = blk - 128;            // plane*4 + band
    int plane = bb >> 2, band = bb & 3;
    int c = plane & 127;
    const float* xp = x + (size_t)plane*16384;
    unsigned short* op = conv + (size_t)plane*16384;
    const float* kw = dw_w + c*9;
    float k0=kw[0],k1=kw[1],k2=kw[2],k3=kw[3],k4=kw[4],k5=kw[5],k6=kw[6],k7=kw[7],k8=kw[8];
    float bias = dw_b[c];
    int q = t & 31;
    int w0 = q*4;
    int rg = t >> 5;
    int h0 = band*32 + rg*4;
    bool le = (q==0), re = (q==31);
    float4 fA, fB, fC; float lA,rA,lB,rB,lC,rC;
    #define LOADROW(hh, f, l, r) { \
      int hc = (hh)<0 ? 0 : ((hh)>127 ? 127 : (hh)); \
      f = *(const float4*)(xp + hc*128 + w0); \
      float lu = __shfl_up(f.w, 1, 32); \
      float rd = __shfl_down(f.x, 1, 32); \
      l = le ? 0.f : lu; \
      r = re ? 0.f : rd; \
      if ((hh)<0 || (hh)>127){ f = make_float4(0.f,0.f,0.f,0.f); l=0.f; r=0.f; } \
    }
    LOADROW(h0-1, fA,lA,rA);
    LOADROW(h0,   fB,lB,rB);
    #pragma unroll
    for (int i=0;i<4;i++){
      LOADROW(h0+1+i, fC,lC,rC);
      float4 o;
      o.x = bias; o.y = bias; o.z = bias; o.w = bias;
      o.x = fmaf(k0,lA,  fmaf(k1,fA.x, fmaf(k2,fA.y, o.x)));
      o.y = fmaf(k0,fA.x,fmaf(k1,fA.y, fmaf(k2,fA.z, o.y)));
      o.z = fmaf(k0,fA.y,fmaf(k1,fA.z, fmaf(k2,fA.w, o.z)));
      o.w = fmaf(k0,fA.z,fmaf(k1,fA.w, fmaf(k2,rA,   o.w)));
      o.x = fmaf(k3,lB,  fmaf(k4,fB.x, fmaf(k5,fB.y, o.x)));
      o.y = fmaf(k3,fB.x,fmaf(k4,fB.y, fmaf(k5,fB.z, o.y)));
      o.z = fmaf(k3,fB.y,fmaf(k4,fB.z, fmaf(k5,fB.w, o.z)));
      o.w = fmaf(k3,fB.z,fmaf(k4,fB.w, fmaf(k5,rB,   o.w)));
      o.x = fmaf(k6,lC,  fmaf(k7,fC.x, fmaf(k8,fC.y, o.x)));
      o.y = fmaf(k6,fC.x,fmaf(k7,fC.y, fmaf(k8,fC.z, o.y)));
      o.z = fmaf(k6,fC.y,fmaf(k7,fC.z, fmaf(k8,fC.w, o.z)));
      o.w = fmaf(k6,fC.z,fmaf(k7,fC.w, fmaf(k8,rC,   o.w)));
      bf16x4 v;
      v[0]=(__bf16)o.x; v[1]=(__bf16)o.y; v[2]=(__bf16)o.z; v[3]=(__bf16)o.w;
      *(bf16x4*)(op + (size_t)(h0+i)*128 + w0) = v;
      fA=fB; lA=lB; rA=rB;
      fB=fC; lB=lC; rB=rC;
    }
    #undef LOADROW
  }
}

// ================= K2: inproj (blocks 0..1023) || modfin (blocks 1024..2047) ====
__global__ __launch_bounds__(512) void k2_inproj_modfin(
  const unsigned short* __restrict__ conv, const unsigned short* __restrict__ in_w_bf,
  const float* __restrict__ in_b, unsigned short* __restrict__ carrier,
  unsigned short* __restrict__ gate,
  const float* __restrict__ projT, const float* __restrict__ ph_b,
  const float* __restrict__ wave_speed, const float* __restrict__ damping,
  float* __restrict__ modT)
{
  int blk = blockIdx.x;
  int t = threadIdx.x;
  if (blk >= 1024){
    // ---- modfin: two 256-thread slices per block ----
    int mblk = (blk - 1024)*2 + (t >= 256 ? 1 : 0);
    int tt = t & 255;
    int c = mblk >> 4, qb = mblk & 15;
    int q = qb*8 + (tt>>5);
    int p0 = (tt & 31)*4;
    float ws0 = wave_speed[0];
    float dmp = damping[0];
    float inv = 1.0f / fmaxf(fabsf(ws0), 1e-6f);
    float dampf = 1.0f + 0.5f*dmp;
    float bc = ph_b[c];
    const float* src = projT + (size_t)c*16384 + q;
    float o[4];
    #pragma unroll
    for (int i=0;i<4;i++){
      float v = src[(size_t)(p0+i)*128] + bc;
      float g = 0.5f*v*(1.0f + erff(v*0.70710678118f));
      float wp = ws0*g;
      o[i] = __cosf(wp) + __sinf(wp)*inv*dampf;
    }
    *(float4*)(modT + ((size_t)c*128 + q)*128 + p0) = make_float4(o[0],o[1],o[2],o[3]);
    return;
  }
  // ---- inproj (single pixel) ----
  __shared__ char A[32768];   // [w][c] swizzled bf16; reused as gate transpose buffer
  int b = blk>>7, h = blk&127;
  const unsigned short* C = conv + (size_t)b*2097152 + h*128;  // + c*16384 + w
  // stage A: transpose conv [c][w] -> LDS [w][c] via 4-channel packs
  {
    int wl = t & 63, grp = t >> 6;   // grp 0..7
    #pragma unroll
    for (int p=0;p<2;p++){
      int w = wl + 64*p;
      #pragma unroll
      for (int q=0;q<4;q++){
        int c0 = (q*8 + grp)*4;
        ushort4 v;
        v.x = C[(size_t)(c0+0)*16384 + w];
        v.y = C[(size_t)(c0+1)*16384 + w];
        v.z = C[(size_t)(c0+2)*16384 + w];
        v.w = C[(size_t)(c0+3)*16384 + w];
        *(ushort4*)(A + swz(w, c0*2)) = v;
      }
    }
  }
  __syncthreads();
  int l = t & 63, wid = t >> 6;
  int wm = wid >> 2, wn = wid & 3;   // 2 x 4 waves, 64x64 quadrants over M=128,N=256
  int lr = l & 15, lk = (l>>4)*8, ld4 = (l>>4)*4;
  fx4 acc[4][4];
  #pragma unroll
  for (int i=0;i<4;i++) for (int j=0;j<4;j++) acc[i][j] = (fx4){0.f,0.f,0.f,0.f};
  run_gemm(
    [&](int mi,int ks)->bf16x8{ return *(const bf16x8*)(A + swz(wm*64+mi*16+lr, (ks*32+lk)*2)); },
    [&](int ni,int ks)->bf16x8{ return *(const bf16x8*)(in_w_bf + (size_t)(wn*64+ni*16+lr)*128 + ks*32+lk); },
    acc);
  __syncthreads();   // done reading A; gate waves will overwrite it
  if (wn < 2){
    // carrier: n in [0,128): store bf16 NCHW
    #pragma unroll
    for (int mi=0;mi<4;mi++)
      #pragma unroll
      for (int ni=0;ni<4;ni++){
        int n = wn*64 + ni*16 + lr;
        int w0 = wm*64 + mi*16 + ld4;
        float bias = in_b[n];
        bf16x4 v;
        v[0]=(__bf16)(acc[mi][ni][0]+bias); v[1]=(__bf16)(acc[mi][ni][1]+bias);
        v[2]=(__bf16)(acc[mi][ni][2]+bias); v[3]=(__bf16)(acc[mi][ni][3]+bias);
        *(bf16x4*)(carrier + (size_t)(b*128+n)*16384 + h*128 + w0) = v;
      }
  } else {
    // gate: n in [128,256): silu, write transposed [w][c] into A
    #pragma unroll
    for (int mi=0;mi<4;mi++)
      #pragma unroll
      for (int ni=0;ni<4;ni++){
        int n = wn*64 + ni*16 + lr;     // 128..255
        int c = n - 128;
        int w0 = wm*64 + mi*16 + ld4;
        float bias = in_b[n];
        #pragma unroll
        for (int r=0;r<4;r++){
          float v = acc[mi][ni][r] + bias;
          float s = v / (1.0f + __expf(-v));
          *(__bf16*)(A + swz(w0+r, c*2)) = (__bf16)s;
        }
      }
  }
  __syncthreads();
  // copy gate LDS [w][c] -> global BHWC bf16, coalesced
  {
    unsigned short* gout = gate + ((size_t)(b*128+h))*16384;   // [w][c]
    int w = t >> 2, cq = (t & 3) * 32;
    #pragma unroll
    for (int i=0;i<4;i++){
      int c0 = cq + i*8;
      int4 v = *(const int4*)(A + swz(w, c0*2));
      *(int4*)(gout + w*128 + c0) = v;
    }
  }
}

// ---------------- fused wave kernel: 4 chained MFMA GEMM phases, TWO slices per block ----
__global__ __launch_bounds__(256) void wave_kernel(
  const unsigned short* __restrict__ carrier,
  const unsigned short* __restrict__ basis,    // [f][pos] bf16
  const unsigned short* __restrict__ basisT,   // [pos][f] bf16
  const float* __restrict__ modT,              // [c][w-freq][h-freq] fp32
  unsigned short* __restrict__ fused)
{
  __shared__ char U0[32768];
  __shared__ char U1[32768];
  int blk = blockIdx.x;          // 0..511
  int c = blk & 127;
  const unsigned short* X0 = carrier + (size_t)blk*16384;
  const unsigned short* X1 = carrier + (size_t)(blk+512)*16384;
  unsigned short* F0 = fused + (size_t)blk*16384;
  unsigned short* F1 = fused + (size_t)(blk+512)*16384;
  int t = threadIdx.x;
  int l = t & 63, wid = t >> 6;
  int wm = wid >> 1, wn = wid & 1;
  int lr = l & 15, lk = (l>>4)*8, ld4 = (l>>4)*4;
  fx4 acc0[4][4], acc1[4][4];

  #define ZACC { _Pragma("unroll") for (int i=0;i<4;i++) _Pragma("unroll") for (int j=0;j<4;j++){ acc0[i][j]=(fx4){0.f,0.f,0.f,0.f}; acc1[i][j]=(fx4){0.f,0.f,0.f,0.f}; } }
  #define TSTORE(BUF0, BUF1) { \
    _Pragma("unroll") for (int mi=0;mi<4;mi++) \
      _Pragma("unroll") for (int ni=0;ni<4;ni++){ \
        int rr = wn*64 + ni*16 + lr, cc = wm*64 + mi*16 + ld4; \
        bf16x4 v0, v1; \
        v0[0]=(__bf16)acc0[mi][ni][0]; v0[1]=(__bf16)acc0[mi][ni][1]; \
        v0[2]=(__bf16)acc0[mi][ni][2]; v0[3]=(__bf16)acc0[mi][ni][3]; \
        v1[0]=(__bf16)acc1[mi][ni][0]; v1[1]=(__bf16)acc1[mi][ni][1]; \
        v1[2]=(__bf16)acc1[mi][ni][2]; v1[3]=(__bf16)acc1[mi][ni][3]; \
        *(bf16x4*)(BUF0 + swz(rr, cc*2)) = v0; \
        *(bf16x4*)(BUF1 + swz(rr, cc*2)) = v1; \
      } }

  // G1: D1[h][m] = X @ Bw^T
  ZACC;
  run_pair_sharedB(
    [&](int mi,int ks)->bf16x8{ return *(const bf16x8*)(X0 + (size_t)(wm*64+mi*16+lr)*128 + ks*32+lk); },
    [&](int mi,int ks)->bf16x8{ return *(const bf16x8*)(X1 + (size_t)(wm*64+mi*16+lr)*128 + ks*32+lk); },
    [&](int ni,int ks)->bf16x8{ return *(const bf16x8*)(basis + (size_t)(wn*64+ni*16+lr)*128 + ks*32+lk); },
    acc0, acc1);
  TSTORE(U0, U1);                // U = D1^T : [m][h]
  __syncthreads();               // bar 1

  // G2: D2[n][m] = Bh @ U^T, then modulate
  ZACC;
  run_pair_sharedA(
    [&](int mi,int ks)->bf16x8{ return *(const bf16x8*)(basis + (size_t)(wm*64+mi*16+lr)*128 + ks*32+lk); },
    [&](int ni,int ks)->bf16x8{ return *(const bf16x8*)(U0 + swz(wn*64+ni*16+lr, (ks*32+lk)*2)); },
    [&](int ni,int ks)->bf16x8{ return *(const bf16x8*)(U1 + swz(wn*64+ni*16+lr, (ks*32+lk)*2)); },
    acc0, acc1);
  {
    const float* Mc = modT + (size_t)c*16384;
    #pragma unroll
    for (int mi=0;mi<4;mi++)
      #pragma unroll
      for (int ni=0;ni<4;ni++){
        int n0 = wm*64 + mi*16 + ld4, m = wn*64 + ni*16 + lr;
        fx4 mv = *(const fx4*)(Mc + (size_t)m*128 + n0);
        acc0[mi][ni] *= mv;
        acc1[mi][ni] *= mv;
      }
  }
  __syncthreads();               // bar 2
  TSTORE(U0, U1);                // U = D2^T : [m][n]
  __syncthreads();               // bar 3

  // G3: D3[m][h] = U @ Bh
  ZACC;
  run_pair_sharedB(
    [&](int mi,int ks)->bf16x8{ return *(const bf16x8*)(U0 + swz(wm*64+mi*16+lr, (ks*32+lk)*2)); },
    [&](int mi,int ks)->bf16x8{ return *(const bf16x8*)(U1 + swz(wm*64+mi*16+lr, (ks*32+lk)*2)); },
    [&](int ni,int ks)->bf16x8{ return *(const bf16x8*)(basisT + (size_t)(wn*64+ni*16+lr)*128 + ks*32+lk); },
    acc0, acc1);
  __syncthreads();               // bar 4
  TSTORE(U0, U1);                // U = D3^T : [h][m]
  __syncthreads();               // bar 5

  // G4: D4[w][h] = BwT @ U^T
  ZACC;
  run_pair_sharedA(
    [&](int mi,int ks)->bf16x8{ return *(const bf16x8*)(basisT + (size_t)(wm*64+mi*16+lr)*128 + ks*32+lk); },
    [&](int ni,int ks)->bf16x8{ return *(const bf16x8*)(U0 + swz(wn*64+ni*16+lr, (ks*32+lk)*2)); },
    [&](int ni,int ks)->bf16x8{ return *(const bf16x8*)(U1 + swz(wn*64+ni*16+lr, (ks*32+lk)*2)); },
    acc0, acc1);
  #pragma unroll
  for (int mi=0;mi<4;mi++)
    #pragma unroll
    for (int ni=0;ni<4;ni++){
      int hh = wn*64 + ni*16 + lr, w0 = wm*64 + mi*16 + ld4;
      bf16x4 v0, v1;
      v0[0]=(__bf16)acc0[mi][ni][0]; v0[1]=(__bf16)acc0[mi][ni][1];
      v0[2]=(__bf16)acc0[mi][ni][2]; v0[3]=(__bf16)acc0[mi][ni][3];
      v1[0]=(__bf16)acc1[mi][ni][0]; v1[1]=(__bf16)acc1[mi][ni][1];
      v1[2]=(__bf16)acc1[mi][ni][2]; v1[3]=(__bf16)acc1[mi][ni][3];
      *(bf16x4*)(F0 + hh*128 + w0) = v0;
      *(bf16x4*)(F1 + hh*128 + w0) = v1;
    }
  #undef ZACC
  #undef TSTORE
}

// ---------------- final: LN * silu(gate) @ out_w^T + b -> out NCHW fp32 ----------------
__global__ __launch_bounds__(256) void final_kernel(
  const unsigned short* __restrict__ fused, const unsigned short* __restrict__ gate,
  const unsigned short* __restrict__ out_w_bf, const float* __restrict__ out_b,
  const float* __restrict__ ln_w, const float* __restrict__ ln_b,
  float* __restrict__ out)
{
  __shared__ char Fl[32768];   // F [c][w] swizzled bf16
  __shared__ char Al[32768];   // act [w][c] swizzled bf16
  __shared__ float red[256], red2[256];
  __shared__ float mu[128], rs[128];
  int blk = blockIdx.x; int b = blk>>7, h = blk&127;
  const unsigned short* Fsrc = fused + (size_t)b*2097152 + h*128;  // + c*16384 + w
  const unsigned short* G = gate + (size_t)blk*16384;              // [w][c]
  int t = threadIdx.x;
  // stage F [c][w]
  {
    int c = t>>1, wq = (t&1)*64;
    #pragma unroll
    for (int i=0;i<8;i++){
      int w0 = wq + i*8;
      int4 v = *(const int4*)(Fsrc + (size_t)c*16384 + w0);
      *(int4*)(Fl + swz(c, w0*2)) = v;
    }
  }
  __syncthreads();
  // LN stats per w (reduce over c)
  {
    int w = t&127, half = t>>7;
    float s=0.f, q=0.f;
    for (int i=0;i<64;i++){
      int c = half*64 + i;
      float f = bf2f(*(const unsigned short*)(Fl + swz(c, w*2)));
      s += f; q = fmaf(f,f,q);
    }
    red[t]=s; red2[t]=q;
  }
  __syncthreads();
  if (t < 128){
    float ss = red[t]+red[t+128], qq = red2[t]+red2[t+128];
    float m = ss*(1.f/128.f);
    float var = qq*(1.f/128.f) - m*m;
    mu[t]=m; rs[t]=rsqrtf(var+1e-5f);
  }
  __syncthreads();
  // act[w][c] = LN(F)*silu_gate
  {
    int w = t>>1, cq = (t&1)*64;
    float m_ = mu[w], r_ = rs[w];
    #pragma unroll
    for (int i=0;i<8;i++){
      int c0 = cq + i*8;
      ushort4 g0 = *(const ushort4*)(G + (size_t)w*128 + c0);
      ushort4 g1 = *(const ushort4*)(G + (size_t)w*128 + c0 + 4);
      unsigned short ov[8];
      unsigned short gv[8] = {g0.x,g0.y,g0.z,g0.w,g1.x,g1.y,g1.z,g1.w};
      #pragma unroll
      for (int j=0;j<8;j++){
        int cc = c0+j;
        float f = bf2f(*(const unsigned short*)(Fl + swz(cc, w*2)));
        float a = fmaf((f-m_)*r_, ln_w[cc], ln_b[cc]) * bf2f(gv[j]);
        ov[j] = f2bf(a);
      }
      *(int4*)(Al + swz(w, c0*2)) = *(const int4*)ov;
    }
  }
  __syncthreads();
  // MFMA: D[w][j] = act @ out_w^T
  int l = t & 63, wid = t >> 6;
  int wm = wid >> 1, wn = wid & 1;
  int lr = l & 15, lk = (l>>4)*8, ld4 = (l>>4)*4;
  fx4 acc[4][4];
  #pragma unroll
  for (int i=0;i<4;i++) for (int j=0;j<4;j++) acc[i][j] = (fx4){0.f,0.f,0.f,0.f};
  run_gemm(
    [&](int mi,int ks)->bf16x8{ return *(const bf16x8*)(Al + swz(wm*64+mi*16+lr, (ks*32+lk)*2)); },
    [&](int ni,int ks)->bf16x8{ return *(const bf16x8*)(out_w_bf + (size_t)(wn*64+ni*16+lr)*128 + ks*32+lk); },
    acc);
  #pragma unroll
  for (int mi=0;mi<4;mi++)
    #pragma unroll
    for (int ni=0;ni<4;ni++){
      int j = wn*64 + ni*16 + lr, w0 = wm*64 + mi*16 + ld4;
      float bj = out_b[j];
      fx4 o = acc[mi][ni];
      o[0]+=bj; o[1]+=bj; o[2]+=bj; o[3]+=bj;
      *(fx4*)(out + ((size_t)(b*128 + j)*128 + h)*128 + w0) = o;
    }
}

extern "C" void kernel_launch(void* const* d_in, const int* in_sizes, int n_in,
                              void* d_out, int out_size, void* d_ws, size_t ws_size,
                              hipStream_t stream)
{
  const float* x      = (const float*)d_in[0];
  const float* dw_w   = (const float*)d_in[1];
  const float* dw_b   = (const float*)d_in[2];
  const float* in_w   = (const float*)d_in[3];
  const float* in_b   = (const float*)d_in[4];
  const float* out_w  = (const float*)d_in[5];
  const float* out_b  = (const float*)d_in[6];
  const float* ln_w   = (const float*)d_in[7];
  const float* ln_b   = (const float*)d_in[8];
  const float* ph_w   = (const float*)d_in[9];
  const float* ph_b   = (const float*)d_in[10];
  const float* wsp    = (const float*)d_in[11];
  const float* dmp    = (const float*)d_in[12];
  const float* fe     = (const float*)d_in[13];
  float* outp = (float*)d_out;

  float* modT  = (float*)d_ws;                 // 2,097,152 f32, [c][w-freq][h-freq]
  float* projT = modT + 2097152;               // 2,097,152 f32
  unsigned short* conv     = (unsigned short*)(projT + 2097152);
  unsigned short* carrier  = conv    + 16777216;
  unsigned short* gate     = carrier + 16777216;
  unsigned short* fusedb   = gate    + 16777216;
  unsigned short* basis_bf = fusedb  + 16777216;
  unsigned short* basisT_bf= basis_bf + 16384;
  unsigned short* in_w_bf  = basisT_bf + 16384;
  unsigned short* out_w_bf = in_w_bf + 32768;

  k1_prep_conv_projk<<<4352,256,0,stream>>>(in_w, ph_w, out_w, fe, x, dw_w, dw_b,
      basis_bf, basisT_bf, in_w_bf, out_w_bf, conv, projT);
  k2_inproj_modfin<<<2048,512,0,stream>>>(conv, in_w_bf, in_b, carrier, gate,
      projT, ph_b, wsp, dmp, modT);
  wave_kernel<<<512,256,0,stream>>>(carrier, basis_bf, basisT_bf, modT, fusedb);
  final_kernel<<<1024,256,0,stream>>>(fusedb, gate, out_w_bf, out_b, ln_w, ln_b, outp);
}

// Round 18
// 156.324 us; speedup vs baseline: 1.1605x; 1.1605x over previous
//
#include <hip/hip_runtime.h>
#include <math.h>

#ifndef M_PI
#define M_PI 3.14159265358979323846
#endif

typedef float fx4 __attribute__((ext_vector_type(4)));
typedef __bf16 bf16x8 __attribute__((ext_vector_type(8)));
typedef __bf16 bf16x4 __attribute__((ext_vector_type(4)));

__device__ __forceinline__ unsigned short f2bf(float f){
  union { float f; unsigned u; } v; v.f = f;
  unsigned r = v.u + 0x7FFFu + ((v.u >> 16) & 1u);
  return (unsigned short)(r >> 16);
}
__device__ __forceinline__ float bf2f(unsigned short u){
  union { unsigned u; float f; } v; v.u = ((unsigned)u) << 16;
  return v.f;
}
// swizzled byte offset within a [row][128] bf16 tile (256 B rows)
__device__ __forceinline__ int swz(int row, int colbyte){
  return row*256 + (colbyte ^ ((row & 7) << 4));
}

// Double-buffered 128-deep (per-wave 64x64) MFMA GEMM core.
template<typename FA, typename FB>
__device__ __forceinline__ void run_gemm(FA la, FB lb, fx4 (&acc)[4][4]){
  bf16x8 a[2][4], b[2][4];
  #pragma unroll
  for (int mi=0;mi<4;mi++){ a[0][mi]=la(mi,0); b[0][mi]=lb(mi,0); }
  #pragma unroll
  for (int ks=0; ks<4; ks++){
    int cur = ks&1, nxt = cur^1;
    if (ks<3){
      #pragma unroll
      for (int mi=0;mi<4;mi++){ a[nxt][mi]=la(mi,ks+1); b[nxt][mi]=lb(mi,ks+1); }
    }
    #pragma unroll
    for (int mi=0;mi<4;mi++)
      #pragma unroll
      for (int ni=0;ni<4;ni++)
        acc[mi][ni] = __builtin_amdgcn_mfma_f32_16x16x32_bf16(a[cur][mi], b[cur][ni], acc[mi][ni], 0, 0, 0);
  }
}

// Two-tile pair, shared B operand: acc0 = A0*B, acc1 = A1*B.
template<typename FA0, typename FA1, typename FB>
__device__ __forceinline__ void run_pair_sharedB(FA0 la0, FA1 la1, FB lb,
                                                 fx4 (&acc0)[4][4], fx4 (&acc1)[4][4]){
  bf16x8 a0[2][4], a1[2][4], b[2][4];
  #pragma unroll
  for (int mi=0;mi<4;mi++){ a0[0][mi]=la0(mi,0); a1[0][mi]=la1(mi,0); b[0][mi]=lb(mi,0); }
  #pragma unroll
  for (int ks=0; ks<4; ks++){
    int cur = ks&1, nxt = cur^1;
    if (ks<3){
      #pragma unroll
      for (int mi=0;mi<4;mi++){ a0[nxt][mi]=la0(mi,ks+1); a1[nxt][mi]=la1(mi,ks+1); b[nxt][mi]=lb(mi,ks+1); }
    }
    #pragma unroll
    for (int mi=0;mi<4;mi++)
      #pragma unroll
      for (int ni=0;ni<4;ni++){
        acc0[mi][ni] = __builtin_amdgcn_mfma_f32_16x16x32_bf16(a0[cur][mi], b[cur][ni], acc0[mi][ni], 0, 0, 0);
        acc1[mi][ni] = __builtin_amdgcn_mfma_f32_16x16x32_bf16(a1[cur][mi], b[cur][ni], acc1[mi][ni], 0, 0, 0);
      }
  }
}

// Two-tile pair, shared A operand: acc0 = A*B0, acc1 = A*B1.
template<typename FA, typename FB0, typename FB1>
__device__ __forceinline__ void run_pair_sharedA(FA la, FB0 lb0, FB1 lb1,
                                                 fx4 (&acc0)[4][4], fx4 (&acc1)[4][4]){
  bf16x8 a[2][4], b0[2][4], b1[2][4];
  #pragma unroll
  for (int mi=0;mi<4;mi++){ a[0][mi]=la(mi,0); b0[0][mi]=lb0(mi,0); b1[0][mi]=lb1(mi,0); }
  #pragma unroll
  for (int ks=0; ks<4; ks++){
    int cur = ks&1, nxt = cur^1;
    if (ks<3){
      #pragma unroll
      for (int mi=0;mi<4;mi++){ a[nxt][mi]=la(mi,ks+1); b0[nxt][mi]=lb0(mi,ks+1); b1[nxt][mi]=lb1(mi,ks+1); }
    }
    #pragma unroll
    for (int mi=0;mi<4;mi++)
      #pragma unroll
      for (int ni=0;ni<4;ni++){
        acc0[mi][ni] = __builtin_amdgcn_mfma_f32_16x16x32_bf16(a[cur][mi], b0[cur][ni], acc0[mi][ni], 0, 0, 0);
        acc1[mi][ni] = __builtin_amdgcn_mfma_f32_16x16x32_bf16(a[cur][mi], b1[cur][ni], acc1[mi][ni], 0, 0, 0);
      }
  }
}

// ================= K1: prep || castfe || dwconv (independent, blockIdx-partitioned) =====
__global__ __launch_bounds__(256) void k1_prep_cast_conv(
    const float* __restrict__ in_w, const float* __restrict__ ph_w,
    const float* __restrict__ out_w, const float* __restrict__ fe,
    const float* __restrict__ x, const float* __restrict__ dw_w,
    const float* __restrict__ dw_b,
    unsigned short* __restrict__ basis_bf, unsigned short* __restrict__ basisT_bf,
    unsigned short* __restrict__ ph_w_bf, unsigned short* __restrict__ in_w_bf,
    unsigned short* __restrict__ out_w_bf, unsigned short* __restrict__ feb,
    unsigned short* __restrict__ conv)
{
  int blk = blockIdx.x;
  int t = threadIdx.x;
  if (blk < 128){
    // ---- prep ----
    if (t >= 128) return;
    int n = blk, h = t;
    double arg = (double)(n*(2*h+1)) * (M_PI/256.0);
    double v = cos(arg) * 0.125;
    if (n==0) v *= 0.7071067811865476;
    unsigned short bv = f2bf((float)v);
    basis_bf[n*128+h]  = bv;
    basisT_bf[h*128+n] = bv;
    ph_w_bf[n*128+h]  = f2bf(ph_w[n*128+h]);
    in_w_bf[n*128+h]        = f2bf(in_w[n*128+h]);
    in_w_bf[(n+128)*128+h]  = f2bf(in_w[(n+128)*128+h]);
    out_w_bf[n*128+h]       = f2bf(out_w[n*128+h]);
    return;
  }
  if (blk < 1152){
    // ---- castfe ----
    int idx = (blk-128)*256 + t;
    const float* s = fe + (size_t)idx*8;
    float4 f0 = *(const float4*)s;
    float4 f1 = *(const float4*)(s+4);
    unsigned short o[8];
    o[0]=f2bf(f0.x); o[1]=f2bf(f0.y); o[2]=f2bf(f0.z); o[3]=f2bf(f0.w);
    o[4]=f2bf(f1.x); o[5]=f2bf(f1.y); o[6]=f2bf(f1.z); o[7]=f2bf(f1.w);
    *(int4*)(feb + (size_t)idx*8) = *(const int4*)o;
    return;
  }
  // ---- dwconv ----
  {
    int bb = blk - 1152;           // plane*4 + band
    int plane = bb >> 2, band = bb & 3;
    int c = plane & 127;
    const float* xp = x + (size_t)plane*16384;
    unsigned short* op = conv + (size_t)plane*16384;
    const float* kw = dw_w + c*9;
    float k0=kw[0],k1=kw[1],k2=kw[2],k3=kw[3],k4=kw[4],k5=kw[5],k6=kw[6],k7=kw[7],k8=kw[8];
    float bias = dw_b[c];
    int q = t & 31;
    int w0 = q*4;
    int rg = t >> 5;
    int h0 = band*32 + rg*4;
    bool le = (q==0), re = (q==31);
    float4 fA, fB, fC; float lA,rA,lB,rB,lC,rC;
    #define LOADROW(hh, f, l, r) { \
      int hc = (hh)<0 ? 0 : ((hh)>127 ? 127 : (hh)); \
      f = *(const float4*)(xp + hc*128 + w0); \
      float lu = __shfl_up(f.w, 1, 32); \
      float rd = __shfl_down(f.x, 1, 32); \
      l = le ? 0.f : lu; \
      r = re ? 0.f : rd; \
      if ((hh)<0 || (hh)>127){ f = make_float4(0.f,0.f,0.f,0.f); l=0.f; r=0.f; } \
    }
    LOADROW(h0-1, fA,lA,rA);
    LOADROW(h0,   fB,lB,rB);
    #pragma unroll
    for (int i=0;i<4;i++){
      LOADROW(h0+1+i, fC,lC,rC);
      float4 o;
      o.x = bias; o.y = bias; o.z = bias; o.w = bias;
      o.x = fmaf(k0,lA,  fmaf(k1,fA.x, fmaf(k2,fA.y, o.x)));
      o.y = fmaf(k0,fA.x,fmaf(k1,fA.y, fmaf(k2,fA.z, o.y)));
      o.z = fmaf(k0,fA.y,fmaf(k1,fA.z, fmaf(k2,fA.w, o.z)));
      o.w = fmaf(k0,fA.z,fmaf(k1,fA.w, fmaf(k2,rA,   o.w)));
      o.x = fmaf(k3,lB,  fmaf(k4,fB.x, fmaf(k5,fB.y, o.x)));
      o.y = fmaf(k3,fB.x,fmaf(k4,fB.y, fmaf(k5,fB.z, o.y)));
      o.z = fmaf(k3,fB.y,fmaf(k4,fB.z, fmaf(k5,fB.w, o.z)));
      o.w = fmaf(k3,fB.z,fmaf(k4,fB.w, fmaf(k5,rB,   o.w)));
      o.x = fmaf(k6,lC,  fmaf(k7,fC.x, fmaf(k8,fC.y, o.x)));
      o.y = fmaf(k6,fC.x,fmaf(k7,fC.y, fmaf(k8,fC.z, o.y)));
      o.z = fmaf(k6,fC.y,fmaf(k7,fC.z, fmaf(k8,fC.w, o.z)));
      o.w = fmaf(k6,fC.z,fmaf(k7,fC.w, fmaf(k8,rC,   o.w)));
      bf16x4 v;
      v[0]=(__bf16)o.x; v[1]=(__bf16)o.y; v[2]=(__bf16)o.z; v[3]=(__bf16)o.w;
      *(bf16x4*)(op + (size_t)(h0+i)*128 + w0) = v;
      fA=fB; lA=lB; rA=rB;
      fB=fC; lB=lC; rB=rC;
    }
    #undef LOADROW
  }
}

// ================= K2: inproj (blocks 0..1023, UNPAIRED) || projk (blocks 1024..1151) ====
__global__ __launch_bounds__(512) void k2_inproj_projk(
  const unsigned short* __restrict__ conv, const unsigned short* __restrict__ in_w_bf,
  const float* __restrict__ in_b, unsigned short* __restrict__ carrier,
  unsigned short* __restrict__ gate,
  const unsigned short* __restrict__ feb, const unsigned short* __restrict__ ph_w_bf,
  float* __restrict__ projT)
{
  int blk = blockIdx.x;
  int t = threadIdx.x;
  if (blk >= 1024){
    // ---- projk (256 active threads) ----
    if (t >= 256) return;
    int r0 = (blk - 1024) * 128;
    int l = t & 63, wid = t >> 6;
    int wm = wid >> 1, wn = wid & 1;
    int lr = l & 15, lk = (l>>4)*8, ld4 = (l>>4)*4;
    fx4 acc[4][4];
    #pragma unroll
    for (int i=0;i<4;i++) for (int j=0;j<4;j++) acc[i][j] = (fx4){0.f,0.f,0.f,0.f};
    run_gemm(
      [&](int mi,int ks)->bf16x8{ return *(const bf16x8*)(feb + (size_t)(r0 + wm*64+mi*16+lr)*128 + ks*32+lk); },
      [&](int ni,int ks)->bf16x8{ return *(const bf16x8*)(ph_w_bf + (size_t)(wn*64+ni*16+lr)*128 + ks*32+lk); },
      acc);
    #pragma unroll
    for (int mi=0;mi<4;mi++)
      #pragma unroll
      for (int ni=0;ni<4;ni++){
        int c = wn*64 + ni*16 + lr;
        int r = r0 + wm*64 + mi*16 + ld4;
        *(fx4*)(projT + (size_t)c*16384 + r) = acc[mi][ni];
      }
    return;
  }
  // ---- inproj (single pixel, r10-validated form) ----
  __shared__ char A[32768];   // [w][c] swizzled bf16; reused as gate transpose buffer
  int b = blk>>7, h = blk&127;
  const unsigned short* C = conv + (size_t)b*2097152 + h*128;  // + c*16384 + w
  // stage A: transpose conv [c][w] -> LDS [w][c] via 4-channel packs
  {
    int wl = t & 63, grp = t >> 6;   // grp 0..7
    #pragma unroll
    for (int p=0;p<2;p++){
      int w = wl + 64*p;
      #pragma unroll
      for (int q=0;q<4;q++){
        int c0 = (q*8 + grp)*4;
        ushort4 v;
        v.x = C[(size_t)(c0+0)*16384 + w];
        v.y = C[(size_t)(c0+1)*16384 + w];
        v.z = C[(size_t)(c0+2)*16384 + w];
        v.w = C[(size_t)(c0+3)*16384 + w];
        *(ushort4*)(A + swz(w, c0*2)) = v;
      }
    }
  }
  __syncthreads();
  int l = t & 63, wid = t >> 6;
  int wm = wid >> 2, wn = wid & 3;   // 2 x 4 waves, 64x64 quadrants over M=128,N=256
  int lr = l & 15, lk = (l>>4)*8, ld4 = (l>>4)*4;
  fx4 acc[4][4];
  #pragma unroll
  for (int i=0;i<4;i++) for (int j=0;j<4;j++) acc[i][j] = (fx4){0.f,0.f,0.f,0.f};
  run_gemm(
    [&](int mi,int ks)->bf16x8{ return *(const bf16x8*)(A + swz(wm*64+mi*16+lr, (ks*32+lk)*2)); },
    [&](int ni,int ks)->bf16x8{ return *(const bf16x8*)(in_w_bf + (size_t)(wn*64+ni*16+lr)*128 + ks*32+lk); },
    acc);
  __syncthreads();   // done reading A; gate waves will overwrite it
  if (wn < 2){
    // carrier: n in [0,128): store bf16 NCHW, 4 consecutive w per 8B store
    #pragma unroll
    for (int mi=0;mi<4;mi++)
      #pragma unroll
      for (int ni=0;ni<4;ni++){
        int n = wn*64 + ni*16 + lr;
        int w0 = wm*64 + mi*16 + ld4;
        float bias = in_b[n];
        ushort4 v;
        v.x=f2bf(acc[mi][ni][0]+bias); v.y=f2bf(acc[mi][ni][1]+bias);
        v.z=f2bf(acc[mi][ni][2]+bias); v.w=f2bf(acc[mi][ni][3]+bias);
        *(ushort4*)(carrier + (size_t)(b*128+n)*16384 + h*128 + w0) = v;
      }
  } else {
    // gate: n in [128,256): silu, write transposed [w][c] into A
    #pragma unroll
    for (int mi=0;mi<4;mi++)
      #pragma unroll
      for (int ni=0;ni<4;ni++){
        int n = wn*64 + ni*16 + lr;     // 128..255
        int c = n - 128;
        int w0 = wm*64 + mi*16 + ld4;
        float bias = in_b[n];
        #pragma unroll
        for (int r=0;r<4;r++){
          float v = acc[mi][ni][r] + bias;
          float s = v / (1.0f + __expf(-v));
          *(unsigned short*)(A + swz(w0+r, c*2)) = f2bf(s);
        }
      }
  }
  __syncthreads();
  // copy gate LDS [w][c] -> global BHWC bf16, coalesced
  {
    unsigned short* gout = gate + ((size_t)(b*128+h))*16384;   // [w][c]
    int w = t >> 2, cq = (t & 3) * 32;
    #pragma unroll
    for (int i=0;i<4;i++){
      int c0 = cq + i*8;
      int4 v = *(const int4*)(A + swz(w, c0*2));
      *(int4*)(gout + w*128 + c0) = v;
    }
  }
}

// ---------------- modfin: factor -> modT[c][q][p]  (q = fe-col = freq-w, p = fe-row = freq-h)
__global__ __launch_bounds__(256) void modfin_kernel(
  const float* __restrict__ projT, const float* __restrict__ ph_b,
  const float* __restrict__ wave_speed, const float* __restrict__ damping,
  float* __restrict__ modT)
{
  int blk = blockIdx.x;
  int c = blk >> 4, qb = blk & 15;
  int t = threadIdx.x;
  int q = qb*8 + (t>>5);
  int p0 = (t & 31)*4;
  float ws0 = wave_speed[0];
  float dmp = damping[0];
  float inv = 1.0f / fmaxf(fabsf(ws0), 1e-6f);
  float dampf = 1.0f + 0.5f*dmp;
  float bc = ph_b[c];
  const float* src = projT + (size_t)c*16384 + q;
  float o[4];
  #pragma unroll
  for (int i=0;i<4;i++){
    float v = src[(size_t)(p0+i)*128] + bc;
    float g = 0.5f*v*(1.0f + erff(v*0.70710678118f));
    float wp = ws0*g;
    o[i] = __cosf(wp) + __sinf(wp)*inv*dampf;
  }
  *(float4*)(modT + ((size_t)c*128 + q)*128 + p0) = make_float4(o[0],o[1],o[2],o[3]);
}

// ---------------- fused wave kernel: 4 chained MFMA GEMM phases, TWO slices per block ----
__global__ __launch_bounds__(256) void wave_kernel(
  const unsigned short* __restrict__ carrier,
  const unsigned short* __restrict__ basis,    // [f][pos] bf16
  const unsigned short* __restrict__ basisT,   // [pos][f] bf16
  const float* __restrict__ modT,              // [c][w-freq][h-freq] fp32
  unsigned short* __restrict__ fused)
{
  __shared__ char U0[32768];
  __shared__ char U1[32768];
  int blk = blockIdx.x;          // 0..511
  int c = blk & 127;
  const unsigned short* X0 = carrier + (size_t)blk*16384;
  const unsigned short* X1 = carrier + (size_t)(blk+512)*16384;
  unsigned short* F0 = fused + (size_t)blk*16384;
  unsigned short* F1 = fused + (size_t)(blk+512)*16384;
  int t = threadIdx.x;
  int l = t & 63, wid = t >> 6;
  int wm = wid >> 1, wn = wid & 1;
  int lr = l & 15, lk = (l>>4)*8, ld4 = (l>>4)*4;
  fx4 acc0[4][4], acc1[4][4];

  #define ZACC { _Pragma("unroll") for (int i=0;i<4;i++) _Pragma("unroll") for (int j=0;j<4;j++){ acc0[i][j]=(fx4){0.f,0.f,0.f,0.f}; acc1[i][j]=(fx4){0.f,0.f,0.f,0.f}; } }
  #define TSTORE(BUF0, BUF1) { \
    _Pragma("unroll") for (int mi=0;mi<4;mi++) \
      _Pragma("unroll") for (int ni=0;ni<4;ni++){ \
        int rr = wn*64 + ni*16 + lr, cc = wm*64 + mi*16 + ld4; \
        bf16x4 v0, v1; \
        v0[0]=(__bf16)acc0[mi][ni][0]; v0[1]=(__bf16)acc0[mi][ni][1]; \
        v0[2]=(__bf16)acc0[mi][ni][2]; v0[3]=(__bf16)acc0[mi][ni][3]; \
        v1[0]=(__bf16)acc1[mi][ni][0]; v1[1]=(__bf16)acc1[mi][ni][1]; \
        v1[2]=(__bf16)acc1[mi][ni][2]; v1[3]=(__bf16)acc1[mi][ni][3]; \
        *(bf16x4*)(BUF0 + swz(rr, cc*2)) = v0; \
        *(bf16x4*)(BUF1 + swz(rr, cc*2)) = v1; \
      } }

  // G1: D1[h][m] = X @ Bw^T
  ZACC;
  run_pair_sharedB(
    [&](int mi,int ks)->bf16x8{ return *(const bf16x8*)(X0 + (size_t)(wm*64+mi*16+lr)*128 + ks*32+lk); },
    [&](int mi,int ks)->bf16x8{ return *(const bf16x8*)(X1 + (size_t)(wm*64+mi*16+lr)*128 + ks*32+lk); },
    [&](int ni,int ks)->bf16x8{ return *(const bf16x8*)(basis + (size_t)(wn*64+ni*16+lr)*128 + ks*32+lk); },
    acc0, acc1);
  TSTORE(U0, U1);                // U = D1^T : [m][h]
  __syncthreads();               // bar 1

  // G2: D2[n][m] = Bh @ U^T, then modulate
  ZACC;
  run_pair_sharedA(
    [&](int mi,int ks)->bf16x8{ return *(const bf16x8*)(basis + (size_t)(wm*64+mi*16+lr)*128 + ks*32+lk); },
    [&](int ni,int ks)->bf16x8{ return *(const bf16x8*)(U0 + swz(wn*64+ni*16+lr, (ks*32+lk)*2)); },
    [&](int ni,int ks)->bf16x8{ return *(const bf16x8*)(U1 + swz(wn*64+ni*16+lr, (ks*32+lk)*2)); },
    acc0, acc1);
  {
    const float* Mc = modT + (size_t)c*16384;
    #pragma unroll
    for (int mi=0;mi<4;mi++)
      #pragma unroll
      for (int ni=0;ni<4;ni++){
        int n0 = wm*64 + mi*16 + ld4, m = wn*64 + ni*16 + lr;
        fx4 mv = *(const fx4*)(Mc + (size_t)m*128 + n0);
        acc0[mi][ni] *= mv;
        acc1[mi][ni] *= mv;
      }
  }
  __syncthreads();               // bar 2
  TSTORE(U0, U1);                // U = D2^T : [m][n]
  __syncthreads();               // bar 3

  // G3: D3[m][h] = U @ Bh
  ZACC;
  run_pair_sharedB(
    [&](int mi,int ks)->bf16x8{ return *(const bf16x8*)(U0 + swz(wm*64+mi*16+lr, (ks*32+lk)*2)); },
    [&](int mi,int ks)->bf16x8{ return *(const bf16x8*)(U1 + swz(wm*64+mi*16+lr, (ks*32+lk)*2)); },
    [&](int ni,int ks)->bf16x8{ return *(const bf16x8*)(basisT + (size_t)(wn*64+ni*16+lr)*128 + ks*32+lk); },
    acc0, acc1);
  __syncthreads();               // bar 4
  TSTORE(U0, U1);                // U = D3^T : [h][m]
  __syncthreads();               // bar 5

  // G4: D4[w][h] = BwT @ U^T
  ZACC;
  run_pair_sharedA(
    [&](int mi,int ks)->bf16x8{ return *(const bf16x8*)(basisT + (size_t)(wm*64+mi*16+lr)*128 + ks*32+lk); },
    [&](int ni,int ks)->bf16x8{ return *(const bf16x8*)(U0 + swz(wn*64+ni*16+lr, (ks*32+lk)*2)); },
    [&](int ni,int ks)->bf16x8{ return *(const bf16x8*)(U1 + swz(wn*64+ni*16+lr, (ks*32+lk)*2)); },
    acc0, acc1);
  #pragma unroll
  for (int mi=0;mi<4;mi++)
    #pragma unroll
    for (int ni=0;ni<4;ni++){
      int hh = wn*64 + ni*16 + lr, w0 = wm*64 + mi*16 + ld4;
      bf16x4 v0, v1;
      v0[0]=(__bf16)acc0[mi][ni][0]; v0[1]=(__bf16)acc0[mi][ni][1];
      v0[2]=(__bf16)acc0[mi][ni][2]; v0[3]=(__bf16)acc0[mi][ni][3];
      v1[0]=(__bf16)acc1[mi][ni][0]; v1[1]=(__bf16)acc1[mi][ni][1];
      v1[2]=(__bf16)acc1[mi][ni][2]; v1[3]=(__bf16)acc1[mi][ni][3];
      *(bf16x4*)(F0 + hh*128 + w0) = v0;
      *(bf16x4*)(F1 + hh*128 + w0) = v1;
    }
  #undef ZACC
  #undef TSTORE
}

// ---------------- final: LN * silu(gate) @ out_w^T + b -> out NCHW fp32 ----------------
__global__ __launch_bounds__(256) void final_kernel(
  const unsigned short* __restrict__ fused, const unsigned short* __restrict__ gate,
  const unsigned short* __restrict__ out_w_bf, const float* __restrict__ out_b,
  const float* __restrict__ ln_w, const float* __restrict__ ln_b,
  float* __restrict__ out)
{
  __shared__ char Fl[32768];   // F [c][w] swizzled bf16
  __shared__ char Al[32768];   // act [w][c] swizzled bf16
  __shared__ float red[256], red2[256];
  __shared__ float mu[128], rs[128];
  int blk = blockIdx.x; int b = blk>>7, h = blk&127;
  const unsigned short* Fsrc = fused + (size_t)b*2097152 + h*128;  // + c*16384 + w
  const unsigned short* G = gate + (size_t)blk*16384;              // [w][c]
  int t = threadIdx.x;
  // stage F [c][w]
  {
    int c = t>>1, wq = (t&1)*64;
    #pragma unroll
    for (int i=0;i<8;i++){
      int w0 = wq + i*8;
      int4 v = *(const int4*)(Fsrc + (size_t)c*16384 + w0);
      *(int4*)(Fl + swz(c, w0*2)) = v;
    }
  }
  __syncthreads();
  // LN stats per w (reduce over c)
  {
    int w = t&127, half = t>>7;
    float s=0.f, q=0.f;
    for (int i=0;i<64;i++){
      int c = half*64 + i;
      float f = bf2f(*(const unsigned short*)(Fl + swz(c, w*2)));
      s += f; q = fmaf(f,f,q);
    }
    red[t]=s; red2[t]=q;
  }
  __syncthreads();
  if (t < 128){
    float ss = red[t]+red[t+128], qq = red2[t]+red2[t+128];
    float m = ss*(1.f/128.f);
    float var = qq*(1.f/128.f) - m*m;
    mu[t]=m; rs[t]=rsqrtf(var+1e-5f);
  }
  __syncthreads();
  // act[w][c] = LN(F)*silu_gate
  {
    int w = t>>1, cq = (t&1)*64;
    float m_ = mu[w], r_ = rs[w];
    #pragma unroll
    for (int i=0;i<8;i++){
      int c0 = cq + i*8;
      ushort4 g0 = *(const ushort4*)(G + (size_t)w*128 + c0);
      ushort4 g1 = *(const ushort4*)(G + (size_t)w*128 + c0 + 4);
      unsigned short ov[8];
      unsigned short gv[8] = {g0.x,g0.y,g0.z,g0.w,g1.x,g1.y,g1.z,g1.w};
      #pragma unroll
      for (int j=0;j<8;j++){
        int cc = c0+j;
        float f = bf2f(*(const unsigned short*)(Fl + swz(cc, w*2)));
        float a = fmaf((f-m_)*r_, ln_w[cc], ln_b[cc]) * bf2f(gv[j]);
        ov[j] = f2bf(a);
      }
      *(int4*)(Al + swz(w, c0*2)) = *(const int4*)ov;
    }
  }
  __syncthreads();
  // MFMA: D[w][j] = act @ out_w^T
  int l = t & 63, wid = t >> 6;
  int wm = wid >> 1, wn = wid & 1;
  int lr = l & 15, lk = (l>>4)*8, ld4 = (l>>4)*4;
  fx4 acc[4][4];
  #pragma unroll
  for (int i=0;i<4;i++) for (int j=0;j<4;j++) acc[i][j] = (fx4){0.f,0.f,0.f,0.f};
  run_gemm(
    [&](int mi,int ks)->bf16x8{ return *(const bf16x8*)(Al + swz(wm*64+mi*16+lr, (ks*32+lk)*2)); },
    [&](int ni,int ks)->bf16x8{ return *(const bf16x8*)(out_w_bf + (size_t)(wn*64+ni*16+lr)*128 + ks*32+lk); },
    acc);
  #pragma unroll
  for (int mi=0;mi<4;mi++)
    #pragma unroll
    for (int ni=0;ni<4;ni++){
      int j = wn*64 + ni*16 + lr, w0 = wm*64 + mi*16 + ld4;
      float bj = out_b[j];
      fx4 o = acc[mi][ni];
      o[0]+=bj; o[1]+=bj; o[2]+=bj; o[3]+=bj;
      *(fx4*)(out + ((size_t)(b*128 + j)*128 + h)*128 + w0) = o;
    }
}

extern "C" void kernel_launch(void* const* d_in, const int* in_sizes, int n_in,
                              void* d_out, int out_size, void* d_ws, size_t ws_size,
                              hipStream_t stream)
{
  const float* x      = (const float*)d_in[0];
  const float* dw_w   = (const float*)d_in[1];
  const float* dw_b   = (const float*)d_in[2];
  const float* in_w   = (const float*)d_in[3];
  const float* in_b   = (const float*)d_in[4];
  const float* out_w  = (const float*)d_in[5];
  const float* out_b  = (const float*)d_in[6];
  const float* ln_w   = (const float*)d_in[7];
  const float* ln_b   = (const float*)d_in[8];
  const float* ph_w   = (const float*)d_in[9];
  const float* ph_b   = (const float*)d_in[10];
  const float* wsp    = (const float*)d_in[11];
  const float* dmp    = (const float*)d_in[12];
  const float* fe     = (const float*)d_in[13];
  float* outp = (float*)d_out;

  float* modT  = (float*)d_ws;                 // 2,097,152 f32, [c][w-freq][h-freq]
  float* projT = modT + 2097152;               // 2,097,152 f32
  unsigned short* feb      = (unsigned short*)(projT + 2097152);  // 2,097,152 bf16
  unsigned short* conv     = feb     + 2097152;
  unsigned short* carrier  = conv    + 16777216;
  unsigned short* gate     = carrier + 16777216;
  unsigned short* fusedb   = gate    + 16777216;
  unsigned short* basis_bf = fusedb  + 16777216;
  unsigned short* basisT_bf= basis_bf + 16384;
  unsigned short* in_w_bf  = basisT_bf + 16384;
  unsigned short* out_w_bf = in_w_bf + 32768;
  unsigned short* ph_w_bf  = out_w_bf + 16384;

  k1_prep_cast_conv<<<5248,256,0,stream>>>(in_w, ph_w, out_w, fe, x, dw_w, dw_b,
      basis_bf, basisT_bf, ph_w_bf, in_w_bf, out_w_bf, feb, conv);
  k2_inproj_projk<<<1152,512,0,stream>>>(conv, in_w_bf, in_b, carrier, gate,
      feb, ph_w_bf, projT);
  modfin_kernel<<<2048,256,0,stream>>>(projT, ph_b, wsp, dmp, modT);
  wave_kernel<<<512,256,0,stream>>>(carrier, basis_bf, basisT_bf, modT, fusedb);
  final_kernel<<<1024,256,0,stream>>>(fusedb, gate, out_w_bf, out_b, ln_w, ln_b, outp);
}